// Round 7
// baseline (260.538 us; speedup 1.0000x reference)
//
#include <hip/hip_runtime.h>

#define B_DIM 4096
#define T_DIM 200
#define D_DIM 128
#define H_DIM 16

extern "C" __global__ __launch_bounds__(512, 4)
void din_fused(const float* __restrict__ query,
               const float* __restrict__ facts,
               const int* __restrict__ mask,
               const float* __restrict__ W1,
               const float* __restrict__ b1,
               const float* __restrict__ W2,
               float* __restrict__ out)
{
    const int b    = blockIdx.x;
    const int tid  = threadIdx.x;
    const int wid  = tid >> 6;         // 0..7
    const int lane = tid & 63;
    const int hq   = tid & 3;          // d-subset {16k + 4*hq + c}
    const int rp   = tid >> 2;         // rowgroup 0..127: rows 2rp, 2rp+1

    __shared__ float weff[H_DIM * D_DIM];   // [h][d]; quad-broadcast reads, conflict-free
    __shared__ float qrow[D_DIM];
    __shared__ float qw[H_DIM];
    __shared__ float sacc[8 * D_DIM];       // qW scratch, then per-wave output partials
    __shared__ float red[16];               // per-wave {m, l}

    const size_t fbase = (size_t)b * (T_DIM * D_DIM);
    const int dof = 4 * hq;

    int  rowi[2]; bool mv[2];
    #pragma unroll
    for (int j = 0; j < 2; ++j) {
        int r = 2 * rp + j;
        mv[j]   = (r < T_DIM);
        rowi[j] = mv[j] ? r : (T_DIM - 1);
    }

    // ---- facts -> registers (fr[2][8] = 64 VGPRs; 64B contiguous per lane-quad) ----
    float4 fr[2][8];
    #pragma unroll
    for (int j = 0; j < 2; ++j)
        #pragma unroll
        for (int k = 0; k < 8; ++k)
            fr[j][k] = *(const float4*)&facts[fbase + (size_t)rowi[j] * D_DIM + 16 * k + dof];

    #pragma unroll
    for (int j = 0; j < 2; ++j)
        if (mv[j]) mv[j] = (mask[(size_t)b * T_DIM + rowi[j]] != 0);

    if (tid < D_DIM) qrow[tid] = query[(size_t)b * D_DIM + tid];
    __syncthreads();                                   // B1: qrow ready

    // ---- W_eff[h][d] = (W1b - W1c)[d][h] + q_d * W1d[d][h] ----
    #pragma unroll
    for (int kk = 0; kk < 4; ++kk) {
        int idx = tid + 512 * kk;                      // = h*128 + d
        int d = idx & 127, h = idx >> 7;
        weff[idx] = W1[(128 + d) * H_DIM + h] - W1[(256 + d) * H_DIM + h]
                  + qrow[d] * W1[(384 + d) * H_DIM + h];
    }
    if (tid < 256) {   // qW partials
        int h = tid & 15, g = tid >> 4;
        float p = 0.f;
        #pragma unroll
        for (int j2 = 0; j2 < 8; ++j2) {
            int d = 8 * g + j2;
            p += qrow[d] * (W1[d * H_DIM + h] + W1[(256 + d) * H_DIM + h]);
        }
        sacc[tid] = p;
    }
    __syncthreads();                                   // B2
    if (tid < H_DIM) {
        float s = b1[tid];
        #pragma unroll
        for (int g = 0; g < 16; ++g) s += sacc[g * 16 + tid];
        qw[tid] = s;
    }
    __syncthreads();                                   // B3: weff + qw ready

    // ---- scoring: 2 rows x 16 h; partial dots reduced across hq BEFORE sigmoid ----
    float score[2] = {0.f, 0.f};
    #pragma unroll
    for (int hc = 0; hc < 4; ++hc) {
        float pre[2][4];
        #pragma unroll
        for (int hi = 0; hi < 4; ++hi)
            #pragma unroll
            for (int r = 0; r < 2; ++r) pre[r][hi] = 0.f;
        #pragma unroll
        for (int k = 0; k < 8; ++k) {
            #pragma unroll
            for (int hi = 0; hi < 4; ++hi) {
                float4 w4 = *(const float4*)&weff[(4 * hc + hi) * D_DIM + 16 * k + dof];
                #pragma unroll
                for (int r = 0; r < 2; ++r) {
                    pre[r][hi] += fr[r][k].x * w4.x + fr[r][k].y * w4.y
                                + fr[r][k].z * w4.z + fr[r][k].w * w4.w;
                }
            }
        }
        #pragma unroll
        for (int hi = 0; hi < 4; ++hi) {
            float q0  = qw[4 * hc + hi];
            float w2v = W2[4 * hc + hi];
            #pragma unroll
            for (int r = 0; r < 2; ++r) {
                float p = pre[r][hi];
                p += __shfl_xor(p, 1);                 // sum the 4 d-subsets
                p += __shfl_xor(p, 2);                 // exact: bit-identical on all quad lanes
                score[r] += w2v / (1.f + __expf(-(q0 + p)));
            }
        }
    }
    #pragma unroll
    for (int r = 0; r < 2; ++r)
        if (!mv[r]) score[r] = -1e30f;

    // ---- per-wave single-shot softmax over its 32 rows ----
    float mloc = fmaxf(score[0], score[1]);
    #pragma unroll
    for (int off = 4; off <= 32; off <<= 1) mloc = fmaxf(mloc, __shfl_xor(mloc, off));
    float w[2], ls = 0.f;
    #pragma unroll
    for (int r = 0; r < 2; ++r) {
        w[r] = mv[r] ? __expf(score[r] - mloc) : 0.f;
        ls += w[r];
    }
    #pragma unroll
    for (int off = 4; off <= 32; off <<= 1) ls += __shfl_xor(ls, off);

    // ---- weighted accumulate straight from registers ----
    float4 acc[8];
    #pragma unroll
    for (int k = 0; k < 8; ++k) {
        acc[k].x = w[0] * fr[0][k].x + w[1] * fr[1][k].x;
        acc[k].y = w[0] * fr[0][k].y + w[1] * fr[1][k].y;
        acc[k].z = w[0] * fr[0][k].z + w[1] * fr[1][k].z;
        acc[k].w = w[0] * fr[0][k].w + w[1] * fr[1][k].w;
    }

    // ---- reduce acc across the wave's 16 quads (butterfly) ----
    #pragma unroll
    for (int off = 4; off <= 32; off <<= 1) {
        #pragma unroll
        for (int k = 0; k < 8; ++k) {
            acc[k].x += __shfl_xor(acc[k].x, off);
            acc[k].y += __shfl_xor(acc[k].y, off);
            acc[k].z += __shfl_xor(acc[k].z, off);
            acc[k].w += __shfl_xor(acc[k].w, off);
        }
    }
    if (lane < 4) {                                    // one lane per hq per wave
        #pragma unroll
        for (int k = 0; k < 8; ++k)
            *(float4*)&sacc[wid * D_DIM + 16 * k + dof] = acc[k];
        if (hq == 0) { red[wid] = mloc; red[8 + wid] = ls; }
    }
    __syncthreads();                                   // B4

    // ---- merge 8 wave partials ----
    if (tid < D_DIM) {
        float M = red[0];
        #pragma unroll
        for (int i = 1; i < 8; ++i) M = fmaxf(M, red[i]);
        float L = 0.f, o = 0.f;
        #pragma unroll
        for (int i = 0; i < 8; ++i) {
            float e = __expf(red[i] - M);
            L += e * red[8 + i];
            o += e * sacc[i * D_DIM + tid];
        }
        out[(size_t)b * D_DIM + tid] = o / L;
    }
}

extern "C" void kernel_launch(void* const* d_in, const int* in_sizes, int n_in,
                              void* d_out, int out_size, void* d_ws, size_t ws_size,
                              hipStream_t stream) {
    const float* query = (const float*)d_in[0];
    const float* facts = (const float*)d_in[1];
    const int*   mask  = (const int*)d_in[2];   // harness delivers bool as int32
    const float* W1    = (const float*)d_in[3];
    const float* b1    = (const float*)d_in[4];
    const float* W2    = (const float*)d_in[5];
    // d_in[6] = b2: dropped (softmax shift-invariant)
    float* out = (float*)d_out;
    (void)in_sizes; (void)n_in; (void)out_size; (void)d_ws; (void)ws_size;

    din_fused<<<dim3(B_DIM), dim3(512), 0, stream>>>(
        query, facts, mask, W1, b1, W2, out);
}